// Round 15
// baseline (173.218 us; speedup 1.0000x reference)
//
#include <hip/hip_runtime.h>
#include <hip/hip_bf16.h>
#include <math.h>

typedef _Float16 f16;
typedef _Float16 half8 __attribute__((ext_vector_type(8)));
typedef _Float16 half4 __attribute__((ext_vector_type(4)));
typedef float f32x4 __attribute__((ext_vector_type(4)));
typedef unsigned int uint;
typedef unsigned int u32x4 __attribute__((ext_vector_type(4)));

#define DIMC 512
#define HEADS 8
#define HD 64
#define BB 4
#define NN 2048
#define MM (BB*NN)        // 8192
#define NQKV (3*DIMC)     // 1536
#define SCALE 0.125f
#define LOG2E 1.44269504f
#define EPSLN 1e-5f

__device__ __forceinline__ void g2l16(const void* g, void* l) {
    __builtin_amdgcn_global_load_lds(
        (const __attribute__((address_space(1))) unsigned int*)g,
        (__attribute__((address_space(3))) unsigned int*)l, 16, 0, 0);
}

// ---------------- prep: LayerNorm (blocks 0..2047) + weight transposes ----------------
__device__ __forceinline__ void ln_rows(const float* __restrict__ x,
                                        const float* __restrict__ gamma,
                                        const float* __restrict__ beta,
                                        f16* __restrict__ xn, int blk) {
    int w = threadIdx.x >> 6;
    int lane = threadIdx.x & 63;
    int row = blk * 4 + w;
    const float* xr = x + (size_t)row * DIMC;
    float4 v0 = ((const float4*)xr)[lane * 2];
    float4 v1 = ((const float4*)xr)[lane * 2 + 1];
    float s = v0.x + v0.y + v0.z + v0.w + v1.x + v1.y + v1.z + v1.w;
#pragma unroll
    for (int off = 1; off < 64; off <<= 1) s += __shfl_xor(s, off);
    float mu = s * (1.0f / DIMC);
    float d0 = v0.x - mu, d1 = v0.y - mu, d2 = v0.z - mu, d3 = v0.w - mu;
    float d4 = v1.x - mu, d5 = v1.y - mu, d6 = v1.z - mu, d7 = v1.w - mu;
    float s2 = d0*d0 + d1*d1 + d2*d2 + d3*d3 + d4*d4 + d5*d5 + d6*d6 + d7*d7;
#pragma unroll
    for (int off = 1; off < 64; off <<= 1) s2 += __shfl_xor(s2, off);
    float rstd = rsqrtf(s2 * (1.0f / DIMC) + EPSLN);
    float4 g0 = ((const float4*)gamma)[lane * 2];
    float4 g1 = ((const float4*)gamma)[lane * 2 + 1];
    float4 b0 = ((const float4*)beta)[lane * 2];
    float4 b1 = ((const float4*)beta)[lane * 2 + 1];
    half8 o;
    o[0] = (f16)(d0 * rstd * g0.x + b0.x);
    o[1] = (f16)(d1 * rstd * g0.y + b0.y);
    o[2] = (f16)(d2 * rstd * g0.z + b0.z);
    o[3] = (f16)(d3 * rstd * g0.w + b0.w);
    o[4] = (f16)(d4 * rstd * g1.x + b1.x);
    o[5] = (f16)(d5 * rstd * g1.y + b1.y);
    o[6] = (f16)(d6 * rstd * g1.z + b1.z);
    o[7] = (f16)(d7 * rstd * g1.w + b1.w);
    ((half8*)(xn + (size_t)row * DIMC))[lane] = o;
}

__device__ __forceinline__ void transp_tile(const float* __restrict__ src,
                                            f16* __restrict__ dst,
                                            int R, int C, int k0, int n0) {
    __shared__ f16 t[32][72];
    int tid = threadIdx.x;
    int rr = tid >> 6, col = tid & 63;
#pragma unroll
    for (int p = 0; p < 8; p++) {
        int r = p * 4 + rr;
        t[r][col] = (f16)src[(size_t)(k0 + r) * C + n0 + col];
    }
    __syncthreads();
    int nl = tid >> 2, kc = (tid & 3) * 8;
    half8 v;
#pragma unroll
    for (int j = 0; j < 8; j++) v[j] = t[kc + j][nl];
    *(half8*)&dst[(size_t)(n0 + nl) * R + k0 + kc] = v;
}

__global__ __launch_bounds__(256) void prep_kernel(const float* __restrict__ x,
                                                   const float* __restrict__ gamma,
                                                   const float* __restrict__ beta,
                                                   const float* __restrict__ wqkv,
                                                   const float* __restrict__ wproj,
                                                   f16* __restrict__ xn,
                                                   f16* __restrict__ wqkvt,
                                                   f16* __restrict__ wprojt) {
    int bid = blockIdx.x;
    if (bid < 2048) {
        ln_rows(x, gamma, beta, xn, bid);
    } else if (bid < 2048 + 384) {
        int b2 = bid - 2048;
        int bx = b2 % 24, by = b2 / 24;
        transp_tile(wqkv, wqkvt, DIMC, NQKV, by * 32, bx * 64);
    } else {
        int b2 = bid - 2048 - 384;
        int bx = b2 % 8, by = b2 / 8;
        transp_tile(wproj, wprojt, DIMC, DIMC, by * 32, bx * 64);
    }
}

// ---------------- shared 128x128 GEMM mainloop (R7: 2-phase dbuf, 1 barrier/kk) ----------
__device__ __forceinline__ void gemm128_loop(const char* Ag, const char* Bg,
                                             f16* As, f16* Bs, f32x4 (&acc)[4][4]) {
    int tid = threadIdx.x;
    int w = tid >> 6, lane = tid & 63, l15 = lane & 15, quad = lane >> 4;
    int wy = w >> 1, wx = w & 1;
    int off0 = w * 1024 + lane * 16;
#define QSTAGE(kk, b) do { \
    _Pragma("unroll") \
    for (int c = 0; c < 2; ++c) { \
        int off = c * 4096 + off0; \
        int row = off >> 6, col = off & 63; \
        g2l16(Ag + (size_t)row * 1024 + (kk) * 64 + col, (char*)As + (b) * 8192 + c * 4096 + w * 1024); \
        g2l16(Bg + (size_t)row * 1024 + (kk) * 64 + col, (char*)Bs + (b) * 8192 + c * 4096 + w * 1024); \
    } } while (0)
    QSTAGE(0, 0);
    __syncthreads();
    for (int kk = 0; kk < 16; ++kk) {
        int cb = kk & 1;
        if (kk < 15) QSTAGE(kk + 1, cb ^ 1);
        half8 af[4], bf[4];
#pragma unroll
        for (int i = 0; i < 4; ++i) {
            af[i] = *(const half8*)((const char*)As + cb * 8192 + ((wy * 64 + i * 16 + l15) << 6) + quad * 16);
            bf[i] = *(const half8*)((const char*)Bs + cb * 8192 + ((wx * 64 + i * 16 + l15) << 6) + quad * 16);
        }
#pragma unroll
        for (int i = 0; i < 4; ++i)
#pragma unroll
            for (int j = 0; j < 4; ++j)
                acc[i][j] = __builtin_amdgcn_mfma_f32_16x16x32_f16(af[i], bf[j], acc[i][j], 0, 0, 0);
        __syncthreads();
    }
#undef QSTAGE
}

// ---------------- QKV GEMM 128x128; Q/K direct stores, V via LDS transpose ----------------
__global__ __launch_bounds__(256) void gemm_qkv(const f16* __restrict__ xn,
                                                const f16* __restrict__ wt,
                                                f16* __restrict__ qb,
                                                f16* __restrict__ kbuf,
                                                f16* __restrict__ vtb) {
    __shared__ __align__(16) f16 As[2 * 128 * 32];
    __shared__ __align__(16) f16 Bs[2 * 128 * 32];
    int tid = threadIdx.x;
    int w = tid >> 6, lane = tid & 63, l15 = lane & 15, quad = lane >> 4;
    int wy = w >> 1, wx = w & 1;
    int m0 = blockIdx.y * 128, c0 = blockIdx.x * 128;
    f32x4 acc[4][4] = {};
    gemm128_loop((const char*)(xn + (size_t)m0 * DIMC),
                 (const char*)(wt + (size_t)c0 * DIMC), As, Bs, acc);
    int bx = blockIdx.x;
    if (bx < 8) {
        const float QS = SCALE * LOG2E;
        f16* dst = (bx < 4) ? qb : kbuf;
        float mul = (bx < 4) ? QS : 1.0f;
        int cb = (bx < 4) ? c0 : c0 - DIMC;
#pragma unroll
        for (int i = 0; i < 4; ++i)
#pragma unroll
            for (int j = 0; j < 4; ++j)
#pragma unroll
                for (int r = 0; r < 4; ++r) {
                    int m = m0 + wy * 64 + i * 16 + quad * 4 + r;
                    int c = cb + wx * 64 + j * 16 + l15;
                    int b = m >> 11, n = m & 2047;
                    int h = c >> 6, d = c & 63;
                    dst[(((size_t)(b * HEADS + h)) * NN + n) * HD + d] = (f16)(acc[i][j][r] * mul);
                }
    } else {
        __syncthreads();
        f16* T = (f16*)As + w * 512;
        int cb = c0 - 2 * DIMC;
        int dl = lane >> 2, mp = lane & 3;
#pragma unroll
        for (int i = 0; i < 4; ++i)
#pragma unroll
            for (int j = 0; j < 4; ++j) {
                half4 hv;
#pragma unroll
                for (int r = 0; r < 4; ++r) hv[r] = (f16)acc[i][j][r];
                *(half4*)&T[l15 * 20 + quad * 4] = hv;
                half4 rv = *(half4*)&T[dl * 20 + mp * 4];
                int c = cb + wx * 64 + j * 16 + dl;
                int m = m0 + wy * 64 + i * 16 + mp * 4;
                int b = m >> 11, n = m & 2047;
                int h = c >> 6, d = c & 63;
                *(half4*)&vtb[(((size_t)(b * HEADS + h)) * HD + d) * NN + n] = rv;
            }
    }
}

// ---------------- Flash attention: in-block split-K x2, 512-thread blocks ----------------
// R1..R5: swizzled LDS, in-reg P (permlane), NCHUNK=1 in-reg normalization.
// R10: g2l16 dbuf staging w/ pre-swizzled global source (verified).
// R12: in-block split-K x2 (best per-dispatch: 44.0us).
// R13 (DROPPED): deferred-PV on split-K slightly negative. R14 (REVERTED):
//     l-sum on VALU moved work into the hotter pipe (VALU 45% > MFMA 30%).
// R15: explicit V-read hoist — load all 8 V fragments right after the QK MFMA
//     cluster, BEFORE the ~300cyc exp2/pack chain (compiler's scheduling
//     window may not hoist 8 ds_read_b128 past 100+ VALU ops). exp chain then
//     covers V-read latency; PV cluster is pure-register at entry. +32 VGPR
//     (av[2][4]) -> ~96, still under the (512,4) 128-cap.
__global__ __launch_bounds__(512, 4) void attn_kernel(const f16* __restrict__ qb,
                                                      const f16* __restrict__ kbuf,
                                                      const f16* __restrict__ vtb,
                                                      f16* __restrict__ ao) {
    __shared__ __align__(16) f16 KV[32768];   // 64KB: dbuf x {K0 8K|K1 8K|V0 8K|V1 8K}
    int id = blockIdx.x;
    int xcd = id & 7, slot = id >> 3;          // slot 0..63
    int bh = xcd * 4 + (slot >> 4);            // all 16 q-tiles of a bh on one XCD
    int qt4 = slot & 15;                       // q-tile 0..15
    int n0 = qt4 * 128;
    int tid = threadIdx.x, w = tid >> 6, lane = tid & 63, l15 = lane & 15, quad = lane >> 4;
    int g = w >> 2, wq = w & 3;                // k-group, q-subtile
    const f16* Kbase = kbuf + (size_t)bh * NN * HD;
    const f16* Vbase = vtb + (size_t)bh * HD * NN;
    const f16* Qbase = qb + (size_t)bh * NN * HD;
    half8 qf[2][2];
#pragma unroll
    for (int qt = 0; qt < 2; ++qt) {
        const f16* qr = Qbase + (size_t)(n0 + wq * 32 + qt * 16 + l15) * HD + quad * 8;
        qf[qt][0] = *(const half8*)qr;
        qf[qt][1] = *(const half8*)(qr + 32);
    }
    f32x4 ot[2][4] = {};
    f32x4 lacc[2] = {};
    half8 ones8;
#pragma unroll
    for (int j = 0; j < 8; ++j) ones8[j] = (f16)1.0f;
    int rx = (l15 & 7) << 4;                   // read-side swizzle constant
    // g2l16 source pre-swizzle (R10): lane -> (row lane>>3, slot lane&7)
    int lrow = lane >> 3;
    int scolb = ((lane & 7) << 4) ^ (lrow << 4);
    // staging: wave w stages combined rows [w*16, w*16+16) of the 128-row K
    // space (2 groups x 64 keys) and the 128-row V space (2 groups x 64 d).
#define ASTAGE(it_, dstb) do { \
    _Pragma("unroll") \
    for (int c = 0; c < 2; ++c) { \
        int base = w * 16 + c * 8; \
        int grp = base >> 6, loc = base & 63; \
        g2l16((const char*)Kbase + (size_t)(grp * 1024 + (it_) * 64 + loc + lrow) * (HD * 2) + scolb, \
              (char*)KV + (dstb) + grp * 8192 + loc * 128); \
        g2l16((const char*)Vbase + (size_t)(loc + lrow) * (NN * 2) + (size_t)(grp * 1024 + (it_) * 64) * 2 + scolb, \
              (char*)KV + (dstb) + 16384 + grp * 8192 + loc * 128); \
    } } while (0)
    ASTAGE(0, 0);
    __syncthreads();
    for (int it = 0; it < NN / 128; ++it) {
        int cur = it & 1;
        char* Kc = (char*)KV + (cur << 15) + g * 8192;
        char* Vc = (char*)KV + (cur << 15) + 16384 + g * 8192;
        if (it < NN / 128 - 1) ASTAGE(it + 1, (cur ^ 1) << 15);
        f32x4 s0[4], s1[4];
        __builtin_amdgcn_s_setprio(1);
#pragma unroll
        for (int kt = 0; kt < 4; ++kt) {
            int rb = (kt * 16 + l15) * 128;
            half8 a0 = *(const half8*)(Kc + rb + ((quad * 16) ^ rx));
            half8 a1 = *(const half8*)(Kc + rb + ((64 + quad * 16) ^ rx));
            f32x4 z0 = {};
            z0 = __builtin_amdgcn_mfma_f32_16x16x32_f16(a0, qf[0][0], z0, 0, 0, 0);
            z0 = __builtin_amdgcn_mfma_f32_16x16x32_f16(a1, qf[0][1], z0, 0, 0, 0);
            s0[kt] = z0;
            f32x4 z1 = {};
            z1 = __builtin_amdgcn_mfma_f32_16x16x32_f16(a0, qf[1][0], z1, 0, 0, 0);
            z1 = __builtin_amdgcn_mfma_f32_16x16x32_f16(a1, qf[1][1], z1, 0, 0, 0);
            s1[kt] = z1;
        }
        __builtin_amdgcn_s_setprio(0);
        // R15: V fragment loads issued HERE — their latency hides under the
        // exp2/pack chain below (explicit hoist; independent of s0/s1).
        half8 av[2][4];
#pragma unroll
        for (int kc = 0; kc < 2; ++kc) {
            int cb = (kc * 64 + quad * 16) ^ rx;
#pragma unroll
            for (int dt = 0; dt < 4; ++dt)
                av[kc][dt] = *(const half8*)(Vc + (dt * 16 + l15) * 128 + cb);
        }
        // exp2 -> packed f16 u32s, fully in-register (R4)
        uint up[2][4][2];
#pragma unroll
        for (int kt = 0; kt < 4; ++kt) {
            up[0][kt][0] = __builtin_bit_cast(uint, __builtin_amdgcn_cvt_pkrtz(
                __builtin_amdgcn_exp2f(s0[kt][0]), __builtin_amdgcn_exp2f(s0[kt][1])));
            up[0][kt][1] = __builtin_bit_cast(uint, __builtin_amdgcn_cvt_pkrtz(
                __builtin_amdgcn_exp2f(s0[kt][2]), __builtin_amdgcn_exp2f(s0[kt][3])));
            up[1][kt][0] = __builtin_bit_cast(uint, __builtin_amdgcn_cvt_pkrtz(
                __builtin_amdgcn_exp2f(s1[kt][0]), __builtin_amdgcn_exp2f(s1[kt][1])));
            up[1][kt][1] = __builtin_bit_cast(uint, __builtin_amdgcn_cvt_pkrtz(
                __builtin_amdgcn_exp2f(s1[kt][2]), __builtin_amdgcn_exp2f(s1[kt][3])));
        }
        // PV + l-sum at K=32: O^T[d][q] += V^T[d][k]*P^T[k][q] (pure-reg entry)
        __builtin_amdgcn_s_setprio(1);
#pragma unroll
        for (int kc = 0; kc < 2; ++kc) {
#pragma unroll
            for (int qt = 0; qt < 2; ++qt) {
                u32x4 pw;
#pragma unroll
                for (int i = 0; i < 2; ++i) {
                    uint x = up[qt][kc * 2][i], y = up[qt][kc * 2 + 1][i];
                    asm volatile("v_permlane32_swap_b32 %0, %1" : "+v"(x), "+v"(y));
                    asm volatile("v_permlane16_swap_b32 %0, %1" : "+v"(x), "+v"(y));
                    pw[i] = x; pw[2 + i] = y;
                }
                half8 pb8 = __builtin_bit_cast(half8, pw);
                lacc[qt] = __builtin_amdgcn_mfma_f32_16x16x32_f16(ones8, pb8, lacc[qt], 0, 0, 0);
#pragma unroll
                for (int dt = 0; dt < 4; ++dt)
                    ot[qt][dt] = __builtin_amdgcn_mfma_f32_16x16x32_f16(av[kc][dt], pb8, ot[qt][dt], 0, 0, 0);
            }
        }
        __builtin_amdgcn_s_setprio(0);
        __syncthreads();   // single barrier: syncs waves + drains DMA for tile it+1
    }
#undef ASTAGE
    // ---- split-K combine: upper k-group waves dump partials, lower waves add ----
    float l0 = lacc[0][0], l1 = lacc[1][0];
    int lsw = (lane & 7) << 4;
    // partials occupy buf0 [0,32KB); l-values at 49152 (inside buf1's V region,
    // last read before the loop's final barrier which all waves passed).
    if (w >= 4) {
        char* dst = (char*)KV + (w - 4) * 8192 + lane * 128;
#pragma unroll
        for (int qt = 0; qt < 2; ++qt)
#pragma unroll
            for (int dt = 0; dt < 4; ++dt)
                *(f32x4*)(dst + (((qt * 4 + dt) * 16) ^ lsw)) = ot[qt][dt];
        float2 lv; lv.x = l0; lv.y = l1;
        *(float2*)((char*)KV + 49152 + ((w - 4) * 64 + lane) * 8) = lv;
    }
    __syncthreads();
    if (w < 4) {
        char* src = (char*)KV + w * 8192 + lane * 128;
#pragma unroll
        for (int qt = 0; qt < 2; ++qt)
#pragma unroll
            for (int dt = 0; dt < 4; ++dt) {
                f32x4 p = *(const f32x4*)(src + (((qt * 4 + dt) * 16) ^ lsw));
                ot[qt][dt] += p;
            }
        float2 lv = *(const float2*)((char*)KV + 49152 + (w * 64 + lane) * 8);
        l0 += lv.x; l1 += lv.y;
    }
    __syncthreads();
    if (w < 4) {
        float inv[2] = { 1.0f / l0, 1.0f / l1 };
        char* Tc = (char*)KV + 32768 + w * 4096;   // buf1 region, 32 rows x 128B
#pragma unroll
        for (int qt = 0; qt < 2; ++qt)
#pragma unroll
            for (int dt = 0; dt < 4; ++dt) {
                half4 hv;
#pragma unroll
                for (int r = 0; r < 4; ++r) hv[r] = (f16)(ot[qt][dt][r] * inv[qt]);
                *(half4*)(Tc + (qt * 16 + l15) * 128 + ((dt * 32 + quad * 8) ^ rx)) = hv;
            }
    }
    __syncthreads();
    if (w < 4) {
        char* Tc = (char*)KV + 32768 + w * 4096;
        int b = bh >> 3, h = bh & 7;
#pragma unroll
        for (int j = 0; j < 4; ++j) {
            int nl = j * 8 + (lane >> 3);
            int d16 = (lane & 7) * 16;
            half8 v = *(const half8*)(Tc + nl * 128 + (d16 ^ ((nl & 7) << 4)));
            int n = n0 + w * 32 + nl;
            *(half8*)&ao[((size_t)(b * NN + n)) * DIMC + h * HD + (lane & 7) * 8] = v;
        }
    }
}

// ---------------- proj GEMM 128x64 + bias + residual (R7: 2-phase dbuf) ----------------
__global__ __launch_bounds__(256) void gemm_proj(const f16* __restrict__ aob,
                                                 const f16* __restrict__ wt,
                                                 const float* __restrict__ x,
                                                 const float* __restrict__ bias,
                                                 float* __restrict__ out) {
    __shared__ __align__(16) f16 As[2 * 128 * 32];
    __shared__ __align__(16) f16 Bs[2 * 64 * 32];
    int tid = threadIdx.x;
    int w = tid >> 6, lane = tid & 63, l15 = lane & 15, quad = lane >> 4;
    int m0 = blockIdx.y * 128, c0 = blockIdx.x * 64;
    const char* Ag = (const char*)(aob + (size_t)m0 * DIMC);
    const char* Bg = (const char*)(wt + (size_t)c0 * DIMC);
    f32x4 acc[2][4] = {};
    int off0 = w * 1024 + lane * 16;
#define PSTAGE(kk, b) do { \
    _Pragma("unroll") \
    for (int c = 0; c < 2; ++c) { \
        int off = c * 4096 + off0; \
        int row = off >> 6, col = off & 63; \
        g2l16(Ag + (size_t)row * 1024 + (kk) * 64 + col, (char*)As + (b) * 8192 + c * 4096 + w * 1024); \
    } \
    { \
        int off = tid * 16; \
        int row = off >> 6, col = off & 63; \
        g2l16(Bg + (size_t)row * 1024 + (kk) * 64 + col, (char*)Bs + (b) * 4096 + w * 1024); \
    } } while (0)
    PSTAGE(0, 0);
    __syncthreads();
    for (int kk = 0; kk < 16; ++kk) {
        int cb = kk & 1;
        if (kk < 15) PSTAGE(kk + 1, cb ^ 1);
        half8 af[2], bf[4];
#pragma unroll
        for (int i = 0; i < 2; ++i)
            af[i] = *(const half8*)((const char*)As + cb * 8192 + ((w * 32 + i * 16 + l15) << 6) + quad * 16);
#pragma unroll
        for (int j = 0; j < 4; ++j)
            bf[j] = *(const half8*)((const char*)Bs + cb * 4096 + ((j * 16 + l15) << 6) + quad * 16);
#pragma unroll
        for (int i = 0; i < 2; ++i)
#pragma unroll
            for (int j = 0; j < 4; ++j)
                acc[i][j] = __builtin_amdgcn_mfma_f32_16x16x32_f16(af[i], bf[j], acc[i][j], 0, 0, 0);
        __syncthreads();
    }
#undef PSTAGE
#pragma unroll
    for (int i = 0; i < 2; ++i)
#pragma unroll
        for (int j = 0; j < 4; ++j)
#pragma unroll
            for (int r = 0; r < 4; ++r) {
                int m = m0 + w * 32 + i * 16 + quad * 4 + r;
                int c = c0 + j * 16 + l15;
                out[(size_t)m * DIMC + c] = x[(size_t)m * DIMC + c] + bias[c] + acc[i][j][r];
            }
}

extern "C" void kernel_launch(void* const* d_in, const int* in_sizes, int n_in,
                              void* d_out, int out_size, void* d_ws, size_t ws_size,
                              hipStream_t stream) {
    (void)in_sizes; (void)n_in; (void)out_size; (void)ws_size;
    const float* x     = (const float*)d_in[0];
    const float* wqkv  = (const float*)d_in[1];
    const float* wproj = (const float*)d_in[2];
    const float* bproj = (const float*)d_in[3];
    const float* gamma = (const float*)d_in[4];
    const float* beta  = (const float*)d_in[5];
    float* out = (float*)d_out;

    char* ws = (char*)d_ws;
    f16* xn     = (f16*)ws;                 ws += (size_t)MM * DIMC * 2;
    f16* wqkvt  = (f16*)ws;                 ws += (size_t)NQKV * DIMC * 2;
    f16* wprojt = (f16*)ws;                 ws += (size_t)DIMC * DIMC * 2;
    f16* qbuf   = (f16*)ws;                 ws += (size_t)MM * DIMC * 2;
    f16* kbuf   = (f16*)ws;                 ws += (size_t)MM * DIMC * 2;
    f16* vtbuf  = (f16*)ws;                 ws += (size_t)MM * DIMC * 2;
    f16* aobuf  = (f16*)ws;                 ws += (size_t)MM * DIMC * 2;

    prep_kernel<<<2048 + 384 + 128, 256, 0, stream>>>(x, gamma, beta, wqkv, wproj,
                                                      xn, wqkvt, wprojt);
    gemm_qkv<<<dim3(NQKV / 128, MM / 128), 256, 0, stream>>>(xn, wqkvt, qbuf, kbuf, vtbuf);
    attn_kernel<<<NN / 128 * BB * HEADS, 512, 0, stream>>>(qbuf, kbuf, vtbuf, aobuf);
    gemm_proj<<<dim3(DIMC / 64, MM / 128), 256, 0, stream>>>(aobuf, wprojt, x, bproj, out);
}

// Round 16
// 155.382 us; speedup vs baseline: 1.1148x; 1.1148x over previous
//
#include <hip/hip_runtime.h>
#include <hip/hip_bf16.h>
#include <math.h>

typedef _Float16 f16;
typedef _Float16 half8 __attribute__((ext_vector_type(8)));
typedef _Float16 half4 __attribute__((ext_vector_type(4)));
typedef float f32x4 __attribute__((ext_vector_type(4)));
typedef unsigned int uint;
typedef unsigned int u32x4 __attribute__((ext_vector_type(4)));

#define DIMC 512
#define HEADS 8
#define HD 64
#define BB 4
#define NN 2048
#define MM (BB*NN)        // 8192
#define NQKV (3*DIMC)     // 1536
#define SCALE 0.125f
#define LOG2E 1.44269504f
#define EPSLN 1e-5f

__device__ __forceinline__ void g2l16(const void* g, void* l) {
    __builtin_amdgcn_global_load_lds(
        (const __attribute__((address_space(1))) unsigned int*)g,
        (__attribute__((address_space(3))) unsigned int*)l, 16, 0, 0);
}

// ---------------- prep: LayerNorm (blocks 0..2047) + weight transposes ----------------
__device__ __forceinline__ void ln_rows(const float* __restrict__ x,
                                        const float* __restrict__ gamma,
                                        const float* __restrict__ beta,
                                        f16* __restrict__ xn, int blk) {
    int w = threadIdx.x >> 6;
    int lane = threadIdx.x & 63;
    int row = blk * 4 + w;
    const float* xr = x + (size_t)row * DIMC;
    float4 v0 = ((const float4*)xr)[lane * 2];
    float4 v1 = ((const float4*)xr)[lane * 2 + 1];
    float s = v0.x + v0.y + v0.z + v0.w + v1.x + v1.y + v1.z + v1.w;
#pragma unroll
    for (int off = 1; off < 64; off <<= 1) s += __shfl_xor(s, off);
    float mu = s * (1.0f / DIMC);
    float d0 = v0.x - mu, d1 = v0.y - mu, d2 = v0.z - mu, d3 = v0.w - mu;
    float d4 = v1.x - mu, d5 = v1.y - mu, d6 = v1.z - mu, d7 = v1.w - mu;
    float s2 = d0*d0 + d1*d1 + d2*d2 + d3*d3 + d4*d4 + d5*d5 + d6*d6 + d7*d7;
#pragma unroll
    for (int off = 1; off < 64; off <<= 1) s2 += __shfl_xor(s2, off);
    float rstd = rsqrtf(s2 * (1.0f / DIMC) + EPSLN);
    float4 g0 = ((const float4*)gamma)[lane * 2];
    float4 g1 = ((const float4*)gamma)[lane * 2 + 1];
    float4 b0 = ((const float4*)beta)[lane * 2];
    float4 b1 = ((const float4*)beta)[lane * 2 + 1];
    half8 o;
    o[0] = (f16)(d0 * rstd * g0.x + b0.x);
    o[1] = (f16)(d1 * rstd * g0.y + b0.y);
    o[2] = (f16)(d2 * rstd * g0.z + b0.z);
    o[3] = (f16)(d3 * rstd * g0.w + b0.w);
    o[4] = (f16)(d4 * rstd * g1.x + b1.x);
    o[5] = (f16)(d5 * rstd * g1.y + b1.y);
    o[6] = (f16)(d6 * rstd * g1.z + b1.z);
    o[7] = (f16)(d7 * rstd * g1.w + b1.w);
    ((half8*)(xn + (size_t)row * DIMC))[lane] = o;
}

__device__ __forceinline__ void transp_tile(const float* __restrict__ src,
                                            f16* __restrict__ dst,
                                            int R, int C, int k0, int n0) {
    __shared__ f16 t[32][72];
    int tid = threadIdx.x;
    int rr = tid >> 6, col = tid & 63;
#pragma unroll
    for (int p = 0; p < 8; p++) {
        int r = p * 4 + rr;
        t[r][col] = (f16)src[(size_t)(k0 + r) * C + n0 + col];
    }
    __syncthreads();
    int nl = tid >> 2, kc = (tid & 3) * 8;
    half8 v;
#pragma unroll
    for (int j = 0; j < 8; j++) v[j] = t[kc + j][nl];
    *(half8*)&dst[(size_t)(n0 + nl) * R + k0 + kc] = v;
}

__global__ __launch_bounds__(256) void prep_kernel(const float* __restrict__ x,
                                                   const float* __restrict__ gamma,
                                                   const float* __restrict__ beta,
                                                   const float* __restrict__ wqkv,
                                                   const float* __restrict__ wproj,
                                                   f16* __restrict__ xn,
                                                   f16* __restrict__ wqkvt,
                                                   f16* __restrict__ wprojt) {
    int bid = blockIdx.x;
    if (bid < 2048) {
        ln_rows(x, gamma, beta, xn, bid);
    } else if (bid < 2048 + 384) {
        int b2 = bid - 2048;
        int bx = b2 % 24, by = b2 / 24;
        transp_tile(wqkv, wqkvt, DIMC, NQKV, by * 32, bx * 64);
    } else {
        int b2 = bid - 2048 - 384;
        int bx = b2 % 8, by = b2 / 8;
        transp_tile(wproj, wprojt, DIMC, DIMC, by * 32, bx * 64);
    }
}

// ---------------- shared 128x128 GEMM mainloop (R7: 2-phase dbuf, 1 barrier/kk) ----------
__device__ __forceinline__ void gemm128_loop(const char* Ag, const char* Bg,
                                             f16* As, f16* Bs, f32x4 (&acc)[4][4]) {
    int tid = threadIdx.x;
    int w = tid >> 6, lane = tid & 63, l15 = lane & 15, quad = lane >> 4;
    int wy = w >> 1, wx = w & 1;
    int off0 = w * 1024 + lane * 16;
#define QSTAGE(kk, b) do { \
    _Pragma("unroll") \
    for (int c = 0; c < 2; ++c) { \
        int off = c * 4096 + off0; \
        int row = off >> 6, col = off & 63; \
        g2l16(Ag + (size_t)row * 1024 + (kk) * 64 + col, (char*)As + (b) * 8192 + c * 4096 + w * 1024); \
        g2l16(Bg + (size_t)row * 1024 + (kk) * 64 + col, (char*)Bs + (b) * 8192 + c * 4096 + w * 1024); \
    } } while (0)
    QSTAGE(0, 0);
    __syncthreads();
    for (int kk = 0; kk < 16; ++kk) {
        int cb = kk & 1;
        if (kk < 15) QSTAGE(kk + 1, cb ^ 1);
        half8 af[4], bf[4];
#pragma unroll
        for (int i = 0; i < 4; ++i) {
            af[i] = *(const half8*)((const char*)As + cb * 8192 + ((wy * 64 + i * 16 + l15) << 6) + quad * 16);
            bf[i] = *(const half8*)((const char*)Bs + cb * 8192 + ((wx * 64 + i * 16 + l15) << 6) + quad * 16);
        }
#pragma unroll
        for (int i = 0; i < 4; ++i)
#pragma unroll
            for (int j = 0; j < 4; ++j)
                acc[i][j] = __builtin_amdgcn_mfma_f32_16x16x32_f16(af[i], bf[j], acc[i][j], 0, 0, 0);
        __syncthreads();
    }
#undef QSTAGE
}

// ---------------- QKV GEMM 128x128; Q/K direct stores, V via LDS transpose ----------------
__global__ __launch_bounds__(256) void gemm_qkv(const f16* __restrict__ xn,
                                                const f16* __restrict__ wt,
                                                f16* __restrict__ qb,
                                                f16* __restrict__ kbuf,
                                                f16* __restrict__ vtb) {
    __shared__ __align__(16) f16 As[2 * 128 * 32];
    __shared__ __align__(16) f16 Bs[2 * 128 * 32];
    int tid = threadIdx.x;
    int w = tid >> 6, lane = tid & 63, l15 = lane & 15, quad = lane >> 4;
    int wy = w >> 1, wx = w & 1;
    int m0 = blockIdx.y * 128, c0 = blockIdx.x * 128;
    f32x4 acc[4][4] = {};
    gemm128_loop((const char*)(xn + (size_t)m0 * DIMC),
                 (const char*)(wt + (size_t)c0 * DIMC), As, Bs, acc);
    int bx = blockIdx.x;
    if (bx < 8) {
        const float QS = SCALE * LOG2E;
        f16* dst = (bx < 4) ? qb : kbuf;
        float mul = (bx < 4) ? QS : 1.0f;
        int cb = (bx < 4) ? c0 : c0 - DIMC;
#pragma unroll
        for (int i = 0; i < 4; ++i)
#pragma unroll
            for (int j = 0; j < 4; ++j)
#pragma unroll
                for (int r = 0; r < 4; ++r) {
                    int m = m0 + wy * 64 + i * 16 + quad * 4 + r;
                    int c = cb + wx * 64 + j * 16 + l15;
                    int b = m >> 11, n = m & 2047;
                    int h = c >> 6, d = c & 63;
                    dst[(((size_t)(b * HEADS + h)) * NN + n) * HD + d] = (f16)(acc[i][j][r] * mul);
                }
    } else {
        __syncthreads();
        f16* T = (f16*)As + w * 512;
        int cb = c0 - 2 * DIMC;
        int dl = lane >> 2, mp = lane & 3;
#pragma unroll
        for (int i = 0; i < 4; ++i)
#pragma unroll
            for (int j = 0; j < 4; ++j) {
                half4 hv;
#pragma unroll
                for (int r = 0; r < 4; ++r) hv[r] = (f16)acc[i][j][r];
                *(half4*)&T[l15 * 20 + quad * 4] = hv;
                half4 rv = *(half4*)&T[dl * 20 + mp * 4];
                int c = cb + wx * 64 + j * 16 + dl;
                int m = m0 + wy * 64 + i * 16 + mp * 4;
                int b = m >> 11, n = m & 2047;
                int h = c >> 6, d = c & 63;
                *(half4*)&vtb[(((size_t)(b * HEADS + h)) * HD + d) * NN + n] = rv;
            }
    }
}

// ---------------- Flash attention: full-K per block, fixed-base softmax ----------------
// R16 = R11 restored (best measured per-dispatch attn, <=42.6us):
//   R1..R5: swizzled LDS, in-reg P (permlane), NCHUNK=1 in-reg normalization.
//   R10: g2l16 dbuf staging w/ pre-swizzled global source.
//   R11: T15 deferred-PV pipeline, launch_bounds(256,2) — VGPRs free up to 256
//        so the carried pbs/avs fragments stay in registers (no spill).
// R12-R15 post-mortems: split-K TLP flat; l-sum-on-VALU flat; V-hoist under
//   the (512,4) 128-VGPR cap SPILLED to scratch (WRITE 8->28MB, attn 60us).
// This structure family's floor is ~42-44us (convoy-serialization, no pipe
// >50%); past it requires the co-designed 8-phase counted-vmcnt rewrite.
__global__ __launch_bounds__(256, 2) void attn_kernel(const f16* __restrict__ qb,
                                                      const f16* __restrict__ kbuf,
                                                      const f16* __restrict__ vtb,
                                                      f16* __restrict__ ao) {
    __shared__ __align__(16) f16 KV[16384];   // 32KB: buf0{K 8K|V 8K} buf1{K 8K|V 8K}
    int id = blockIdx.x;
    int xcd = id & 7, slot = id >> 3;          // slot 0..63
    int bh = xcd * 4 + (slot >> 4);            // all 16 q-tiles of a bh on one XCD
    int qt4 = slot & 15;                       // q-tile 0..15
    int n0 = qt4 * 128;
    int tid = threadIdx.x, w = tid >> 6, lane = tid & 63, l15 = lane & 15, quad = lane >> 4;
    const f16* Kbase = kbuf + (size_t)bh * NN * HD;
    const f16* Vbase = vtb + (size_t)bh * HD * NN;
    const f16* Qbase = qb + (size_t)bh * NN * HD;
    half8 qf[2][2];
#pragma unroll
    for (int qt = 0; qt < 2; ++qt) {
        const f16* qr = Qbase + (size_t)(n0 + w * 32 + qt * 16 + l15) * HD + quad * 8;
        qf[qt][0] = *(const half8*)qr;
        qf[qt][1] = *(const half8*)(qr + 32);
    }
    f32x4 ot[2][4] = {};
    f32x4 lacc[2] = {};
    half8 ones8;
#pragma unroll
    for (int j = 0; j < 8; ++j) ones8[j] = (f16)1.0f;
    int rx = (l15 & 7) << 4;                   // read-side swizzle constant
    // g2l16 source pre-swizzle (R10): lane -> (row lane>>3, slot lane&7)
    int lrow = lane >> 3;
    int scolb = ((lane & 7) << 4) ^ (lrow << 4);
    int rbase = w * 16;
    {
        char* K0 = (char*)KV;
        char* V0 = (char*)KV + 8192;
#pragma unroll
        for (int c = 0; c < 2; ++c) {
            int r0 = rbase + c * 8;
            g2l16((const char*)Kbase + (size_t)(r0 + lrow) * (HD * 2) + scolb,
                  K0 + r0 * 128);
            g2l16((const char*)Vbase + (size_t)(r0 + lrow) * (NN * 2) + scolb,
                  V0 + r0 * 128);
        }
    }
    __syncthreads();
    u32x4 pbs[2][2];     // deferred P fragments [kc][qt]
    half8 avs[2][4];     // deferred V fragments [kc][dt]
    for (int it = 0; it < NN / 64; ++it) {
        int cur = it & 1;
        char* Kc = (char*)KV + (cur << 14);
        char* Vc = Kc + 8192;
        if (it < NN / 64 - 1) {
            char* Kn = (char*)KV + ((cur ^ 1) << 14);
            char* Vn = Kn + 8192;
            int k0 = (it + 1) * 64;
#pragma unroll
            for (int c = 0; c < 2; ++c) {
                int r0 = rbase + c * 8;
                g2l16((const char*)Kbase + (size_t)(k0 + r0 + lrow) * (HD * 2) + scolb,
                      Kn + r0 * 128);
                g2l16((const char*)Vbase + (size_t)(r0 + lrow) * (NN * 2) + k0 * 2 + scolb,
                      Vn + r0 * 128);
            }
        }
        // deferred PV(it-1): pure-register MFMAs — interleaves with QK(it)'s
        // ds_read latency below (scheduler hoists the loads)
        if (it > 0) {
            __builtin_amdgcn_s_setprio(1);
#pragma unroll
            for (int kc = 0; kc < 2; ++kc)
#pragma unroll
                for (int qt = 0; qt < 2; ++qt) {
                    half8 pb8 = __builtin_bit_cast(half8, pbs[kc][qt]);
                    lacc[qt] = __builtin_amdgcn_mfma_f32_16x16x32_f16(ones8, pb8, lacc[qt], 0, 0, 0);
#pragma unroll
                    for (int dt = 0; dt < 4; ++dt)
                        ot[qt][dt] = __builtin_amdgcn_mfma_f32_16x16x32_f16(avs[kc][dt], pb8, ot[qt][dt], 0, 0, 0);
                }
            __builtin_amdgcn_s_setprio(0);
        }
        // QK(it)
        f32x4 s0[4], s1[4];
        __builtin_amdgcn_s_setprio(1);
#pragma unroll
        for (int kt = 0; kt < 4; ++kt) {
            int rb = (kt * 16 + l15) * 128;
            half8 a0 = *(const half8*)(Kc + rb + ((quad * 16) ^ rx));
            half8 a1 = *(const half8*)(Kc + rb + ((64 + quad * 16) ^ rx));
            f32x4 z0 = {};
            z0 = __builtin_amdgcn_mfma_f32_16x16x32_f16(a0, qf[0][0], z0, 0, 0, 0);
            z0 = __builtin_amdgcn_mfma_f32_16x16x32_f16(a1, qf[0][1], z0, 0, 0, 0);
            s0[kt] = z0;
            f32x4 z1 = {};
            z1 = __builtin_amdgcn_mfma_f32_16x16x32_f16(a0, qf[1][0], z1, 0, 0, 0);
            z1 = __builtin_amdgcn_mfma_f32_16x16x32_f16(a1, qf[1][1], z1, 0, 0, 0);
            s1[kt] = z1;
        }
        __builtin_amdgcn_s_setprio(0);
        // exp2 -> packed f16 u32s, fully in-register (R4)
        uint up[2][4][2];
#pragma unroll
        for (int kt = 0; kt < 4; ++kt) {
            up[0][kt][0] = __builtin_bit_cast(uint, __builtin_amdgcn_cvt_pkrtz(
                __builtin_amdgcn_exp2f(s0[kt][0]), __builtin_amdgcn_exp2f(s0[kt][1])));
            up[0][kt][1] = __builtin_bit_cast(uint, __builtin_amdgcn_cvt_pkrtz(
                __builtin_amdgcn_exp2f(s0[kt][2]), __builtin_amdgcn_exp2f(s0[kt][3])));
            up[1][kt][0] = __builtin_bit_cast(uint, __builtin_amdgcn_cvt_pkrtz(
                __builtin_amdgcn_exp2f(s1[kt][0]), __builtin_amdgcn_exp2f(s1[kt][1])));
            up[1][kt][1] = __builtin_bit_cast(uint, __builtin_amdgcn_cvt_pkrtz(
                __builtin_amdgcn_exp2f(s1[kt][2]), __builtin_amdgcn_exp2f(s1[kt][3])));
        }
        // read V(it) into regs + build P(it) fragments; MFMAs run next iter
#pragma unroll
        for (int kc = 0; kc < 2; ++kc) {
            int cb = (kc * 64 + quad * 16) ^ rx;
#pragma unroll
            for (int dt = 0; dt < 4; ++dt)
                avs[kc][dt] = *(const half8*)(Vc + (dt * 16 + l15) * 128 + cb);
#pragma unroll
            for (int qt = 0; qt < 2; ++qt) {
                u32x4 pw;
#pragma unroll
                for (int i = 0; i < 2; ++i) {
                    uint x = up[qt][kc * 2][i], y = up[qt][kc * 2 + 1][i];
                    asm volatile("v_permlane32_swap_b32 %0, %1" : "+v"(x), "+v"(y));
                    asm volatile("v_permlane16_swap_b32 %0, %1" : "+v"(x), "+v"(y));
                    pw[i] = x; pw[2 + i] = y;
                }
                pbs[kc][qt] = pw;
            }
        }
        __syncthreads();   // single barrier: syncs waves + drains DMA for tile it+1
    }
    // final PV(31)
    __builtin_amdgcn_s_setprio(1);
#pragma unroll
    for (int kc = 0; kc < 2; ++kc)
#pragma unroll
        for (int qt = 0; qt < 2; ++qt) {
            half8 pb8 = __builtin_bit_cast(half8, pbs[kc][qt]);
            lacc[qt] = __builtin_amdgcn_mfma_f32_16x16x32_f16(ones8, pb8, lacc[qt], 0, 0, 0);
#pragma unroll
            for (int dt = 0; dt < 4; ++dt)
                ot[qt][dt] = __builtin_amdgcn_mfma_f32_16x16x32_f16(avs[kc][dt], pb8, ot[qt][dt], 0, 0, 0);
        }
    __builtin_amdgcn_s_setprio(0);
    // R5: in-register normalization — lacc col=l15=q matches ot col=q (same lane)
    float inv[2] = { 1.0f / lacc[0][0], 1.0f / lacc[1][0] };
    char* Tc = (char*)KV + w * 4096;         // per-wave 32 rows x 128B, swizzled (buf0 region)
#pragma unroll
    for (int qt = 0; qt < 2; ++qt)
#pragma unroll
        for (int dt = 0; dt < 4; ++dt) {
            half4 hv;
#pragma unroll
            for (int r = 0; r < 4; ++r) hv[r] = (f16)(ot[qt][dt][r] * inv[qt]);
            *(half4*)(Tc + (qt * 16 + l15) * 128 + ((dt * 32 + quad * 8) ^ rx)) = hv;
        }
    __syncthreads();
    int b = bh >> 3, h = bh & 7;
#pragma unroll
    for (int j = 0; j < 4; ++j) {
        int nl = j * 8 + (lane >> 3);
        int d16 = (lane & 7) * 16;
        half8 v = *(const half8*)(Tc + nl * 128 + (d16 ^ ((nl & 7) << 4)));
        int n = n0 + w * 32 + nl;
        *(half8*)&ao[((size_t)(b * NN + n)) * DIMC + h * HD + (lane & 7) * 8] = v;
    }
}

// ---------------- proj GEMM 128x64 + bias + residual (R7: 2-phase dbuf) ----------------
__global__ __launch_bounds__(256) void gemm_proj(const f16* __restrict__ aob,
                                                 const f16* __restrict__ wt,
                                                 const float* __restrict__ x,
                                                 const float* __restrict__ bias,
                                                 float* __restrict__ out) {
    __shared__ __align__(16) f16 As[2 * 128 * 32];
    __shared__ __align__(16) f16 Bs[2 * 64 * 32];
    int tid = threadIdx.x;
    int w = tid >> 6, lane = tid & 63, l15 = lane & 15, quad = lane >> 4;
    int m0 = blockIdx.y * 128, c0 = blockIdx.x * 64;
    const char* Ag = (const char*)(aob + (size_t)m0 * DIMC);
    const char* Bg = (const char*)(wt + (size_t)c0 * DIMC);
    f32x4 acc[2][4] = {};
    int off0 = w * 1024 + lane * 16;
#define PSTAGE(kk, b) do { \
    _Pragma("unroll") \
    for (int c = 0; c < 2; ++c) { \
        int off = c * 4096 + off0; \
        int row = off >> 6, col = off & 63; \
        g2l16(Ag + (size_t)row * 1024 + (kk) * 64 + col, (char*)As + (b) * 8192 + c * 4096 + w * 1024); \
    } \
    { \
        int off = tid * 16; \
        int row = off >> 6, col = off & 63; \
        g2l16(Bg + (size_t)row * 1024 + (kk) * 64 + col, (char*)Bs + (b) * 4096 + w * 1024); \
    } } while (0)
    PSTAGE(0, 0);
    __syncthreads();
    for (int kk = 0; kk < 16; ++kk) {
        int cb = kk & 1;
        if (kk < 15) PSTAGE(kk + 1, cb ^ 1);
        half8 af[2], bf[4];
#pragma unroll
        for (int i = 0; i < 2; ++i)
            af[i] = *(const half8*)((const char*)As + cb * 8192 + ((w * 32 + i * 16 + l15) << 6) + quad * 16);
#pragma unroll
        for (int j = 0; j < 4; ++j)
            bf[j] = *(const half8*)((const char*)Bs + cb * 4096 + ((j * 16 + l15) << 6) + quad * 16);
#pragma unroll
        for (int i = 0; i < 2; ++i)
#pragma unroll
            for (int j = 0; j < 4; ++j)
                acc[i][j] = __builtin_amdgcn_mfma_f32_16x16x32_f16(af[i], bf[j], acc[i][j], 0, 0, 0);
        __syncthreads();
    }
#undef PSTAGE
#pragma unroll
    for (int i = 0; i < 2; ++i)
#pragma unroll
        for (int j = 0; j < 4; ++j)
#pragma unroll
            for (int r = 0; r < 4; ++r) {
                int m = m0 + w * 32 + i * 16 + quad * 4 + r;
                int c = c0 + j * 16 + l15;
                out[(size_t)m * DIMC + c] = x[(size_t)m * DIMC + c] + bias[c] + acc[i][j][r];
            }
}

extern "C" void kernel_launch(void* const* d_in, const int* in_sizes, int n_in,
                              void* d_out, int out_size, void* d_ws, size_t ws_size,
                              hipStream_t stream) {
    (void)in_sizes; (void)n_in; (void)out_size; (void)ws_size;
    const float* x     = (const float*)d_in[0];
    const float* wqkv  = (const float*)d_in[1];
    const float* wproj = (const float*)d_in[2];
    const float* bproj = (const float*)d_in[3];
    const float* gamma = (const float*)d_in[4];
    const float* beta  = (const float*)d_in[5];
    float* out = (float*)d_out;

    char* ws = (char*)d_ws;
    f16* xn     = (f16*)ws;                 ws += (size_t)MM * DIMC * 2;
    f16* wqkvt  = (f16*)ws;                 ws += (size_t)NQKV * DIMC * 2;
    f16* wprojt = (f16*)ws;                 ws += (size_t)DIMC * DIMC * 2;
    f16* qbuf   = (f16*)ws;                 ws += (size_t)MM * DIMC * 2;
    f16* kbuf   = (f16*)ws;                 ws += (size_t)MM * DIMC * 2;
    f16* vtbuf  = (f16*)ws;                 ws += (size_t)MM * DIMC * 2;
    f16* aobuf  = (f16*)ws;                 ws += (size_t)MM * DIMC * 2;

    prep_kernel<<<2048 + 384 + 128, 256, 0, stream>>>(x, gamma, beta, wqkv, wproj,
                                                      xn, wqkvt, wprojt);
    gemm_qkv<<<dim3(NQKV / 128, MM / 128), 256, 0, stream>>>(xn, wqkvt, qbuf, kbuf, vtbuf);
    attn_kernel<<<NN / 128 * BB * HEADS, 256, 0, stream>>>(qbuf, kbuf, vtbuf, aobuf);
    gemm_proj<<<dim3(DIMC / 64, MM / 128), 256, 0, stream>>>(aobuf, wprojt, x, bproj, out);
}

// Round 17
// 153.647 us; speedup vs baseline: 1.1274x; 1.0113x over previous
//
#include <hip/hip_runtime.h>
#include <hip/hip_bf16.h>
#include <math.h>

typedef _Float16 f16;
typedef _Float16 half8 __attribute__((ext_vector_type(8)));
typedef _Float16 half4 __attribute__((ext_vector_type(4)));
typedef float f32x4 __attribute__((ext_vector_type(4)));
typedef unsigned int uint;
typedef unsigned int u32x4 __attribute__((ext_vector_type(4)));

#define DIMC 512
#define HEADS 8
#define HD 64
#define BB 4
#define NN 2048
#define MM (BB*NN)        // 8192
#define NQKV (3*DIMC)     // 1536
#define SCALE 0.125f
#define LOG2E 1.44269504f
#define EPSLN 1e-5f

__device__ __forceinline__ void g2l16(const void* g, void* l) {
    __builtin_amdgcn_global_load_lds(
        (const __attribute__((address_space(1))) unsigned int*)g,
        (__attribute__((address_space(3))) unsigned int*)l, 16, 0, 0);
}

// ---------------- prep: LayerNorm (blocks 0..2047) + weight transposes ----------------
__device__ __forceinline__ void ln_rows(const float* __restrict__ x,
                                        const float* __restrict__ gamma,
                                        const float* __restrict__ beta,
                                        f16* __restrict__ xn, int blk) {
    int w = threadIdx.x >> 6;
    int lane = threadIdx.x & 63;
    int row = blk * 4 + w;
    const float* xr = x + (size_t)row * DIMC;
    float4 v0 = ((const float4*)xr)[lane * 2];
    float4 v1 = ((const float4*)xr)[lane * 2 + 1];
    float s = v0.x + v0.y + v0.z + v0.w + v1.x + v1.y + v1.z + v1.w;
#pragma unroll
    for (int off = 1; off < 64; off <<= 1) s += __shfl_xor(s, off);
    float mu = s * (1.0f / DIMC);
    float d0 = v0.x - mu, d1 = v0.y - mu, d2 = v0.z - mu, d3 = v0.w - mu;
    float d4 = v1.x - mu, d5 = v1.y - mu, d6 = v1.z - mu, d7 = v1.w - mu;
    float s2 = d0*d0 + d1*d1 + d2*d2 + d3*d3 + d4*d4 + d5*d5 + d6*d6 + d7*d7;
#pragma unroll
    for (int off = 1; off < 64; off <<= 1) s2 += __shfl_xor(s2, off);
    float rstd = rsqrtf(s2 * (1.0f / DIMC) + EPSLN);
    float4 g0 = ((const float4*)gamma)[lane * 2];
    float4 g1 = ((const float4*)gamma)[lane * 2 + 1];
    float4 b0 = ((const float4*)beta)[lane * 2];
    float4 b1 = ((const float4*)beta)[lane * 2 + 1];
    half8 o;
    o[0] = (f16)(d0 * rstd * g0.x + b0.x);
    o[1] = (f16)(d1 * rstd * g0.y + b0.y);
    o[2] = (f16)(d2 * rstd * g0.z + b0.z);
    o[3] = (f16)(d3 * rstd * g0.w + b0.w);
    o[4] = (f16)(d4 * rstd * g1.x + b1.x);
    o[5] = (f16)(d5 * rstd * g1.y + b1.y);
    o[6] = (f16)(d6 * rstd * g1.z + b1.z);
    o[7] = (f16)(d7 * rstd * g1.w + b1.w);
    ((half8*)(xn + (size_t)row * DIMC))[lane] = o;
}

__device__ __forceinline__ void transp_tile(const float* __restrict__ src,
                                            f16* __restrict__ dst,
                                            int R, int C, int k0, int n0) {
    __shared__ f16 t[32][72];
    int tid = threadIdx.x;
    int rr = tid >> 6, col = tid & 63;
#pragma unroll
    for (int p = 0; p < 8; p++) {
        int r = p * 4 + rr;
        t[r][col] = (f16)src[(size_t)(k0 + r) * C + n0 + col];
    }
    __syncthreads();
    int nl = tid >> 2, kc = (tid & 3) * 8;
    half8 v;
#pragma unroll
    for (int j = 0; j < 8; j++) v[j] = t[kc + j][nl];
    *(half8*)&dst[(size_t)(n0 + nl) * R + k0 + kc] = v;
}

__global__ __launch_bounds__(256) void prep_kernel(const float* __restrict__ x,
                                                   const float* __restrict__ gamma,
                                                   const float* __restrict__ beta,
                                                   const float* __restrict__ wqkv,
                                                   const float* __restrict__ wproj,
                                                   f16* __restrict__ xn,
                                                   f16* __restrict__ wqkvt,
                                                   f16* __restrict__ wprojt) {
    int bid = blockIdx.x;
    if (bid < 2048) {
        ln_rows(x, gamma, beta, xn, bid);
    } else if (bid < 2048 + 384) {
        int b2 = bid - 2048;
        int bx = b2 % 24, by = b2 / 24;
        transp_tile(wqkv, wqkvt, DIMC, NQKV, by * 32, bx * 64);
    } else {
        int b2 = bid - 2048 - 384;
        int bx = b2 % 8, by = b2 / 8;
        transp_tile(wproj, wprojt, DIMC, DIMC, by * 32, bx * 64);
    }
}

// ---------------- shared 128x128 GEMM mainloop (R7: 2-phase dbuf, 1 barrier/kk) ----------
__device__ __forceinline__ void gemm128_loop(const char* Ag, const char* Bg,
                                             f16* As, f16* Bs, f32x4 (&acc)[4][4]) {
    int tid = threadIdx.x;
    int w = tid >> 6, lane = tid & 63, l15 = lane & 15, quad = lane >> 4;
    int wy = w >> 1, wx = w & 1;
    int off0 = w * 1024 + lane * 16;
#define QSTAGE(kk, b) do { \
    _Pragma("unroll") \
    for (int c = 0; c < 2; ++c) { \
        int off = c * 4096 + off0; \
        int row = off >> 6, col = off & 63; \
        g2l16(Ag + (size_t)row * 1024 + (kk) * 64 + col, (char*)As + (b) * 8192 + c * 4096 + w * 1024); \
        g2l16(Bg + (size_t)row * 1024 + (kk) * 64 + col, (char*)Bs + (b) * 8192 + c * 4096 + w * 1024); \
    } } while (0)
    QSTAGE(0, 0);
    __syncthreads();
    for (int kk = 0; kk < 16; ++kk) {
        int cb = kk & 1;
        if (kk < 15) QSTAGE(kk + 1, cb ^ 1);
        half8 af[4], bf[4];
#pragma unroll
        for (int i = 0; i < 4; ++i) {
            af[i] = *(const half8*)((const char*)As + cb * 8192 + ((wy * 64 + i * 16 + l15) << 6) + quad * 16);
            bf[i] = *(const half8*)((const char*)Bs + cb * 8192 + ((wx * 64 + i * 16 + l15) << 6) + quad * 16);
        }
#pragma unroll
        for (int i = 0; i < 4; ++i)
#pragma unroll
            for (int j = 0; j < 4; ++j)
                acc[i][j] = __builtin_amdgcn_mfma_f32_16x16x32_f16(af[i], bf[j], acc[i][j], 0, 0, 0);
        __syncthreads();
    }
#undef QSTAGE
}

// ---------------- QKV GEMM 128x128; Q/K via LDS-transpose half8 stores (R17) ------------
__global__ __launch_bounds__(256) void gemm_qkv(const f16* __restrict__ xn,
                                                const f16* __restrict__ wt,
                                                f16* __restrict__ qb,
                                                f16* __restrict__ kbuf,
                                                f16* __restrict__ vtb) {
    __shared__ __align__(16) f16 As[2 * 128 * 32];
    __shared__ __align__(16) f16 Bs[2 * 128 * 32];
    int tid = threadIdx.x;
    int w = tid >> 6, lane = tid & 63, l15 = lane & 15, quad = lane >> 4;
    int wy = w >> 1, wx = w & 1;
    int m0 = blockIdx.y * 128, c0 = blockIdx.x * 128;
    f32x4 acc[4][4] = {};
    gemm128_loop((const char*)(xn + (size_t)m0 * DIMC),
                 (const char*)(wt + (size_t)c0 * DIMC), As, Bs, acc);
    int bx = blockIdx.x;
    if (bx < 8) {
        // R17: transpose each 16x64 (m x d) fragment through wave-private LDS;
        // store full 128B d-rows as half8 (64 scalar stores -> 8 vector stores).
        const float QS = SCALE * LOG2E;
        f16* dst = (bx < 4) ? qb : kbuf;
        float mul = (bx < 4) ? QS : 1.0f;
        int cb = (bx < 4) ? c0 : c0 - DIMC;
        int h = (cb + wx * 64) >> 6;           // per-wave head (64-wide slice)
        f16* T = (f16*)As + w * 1152;          // wave-private 16 x 72
#pragma unroll
        for (int i = 0; i < 4; ++i) {
#pragma unroll
            for (int j = 0; j < 4; ++j)
#pragma unroll
                for (int r = 0; r < 4; ++r)
                    T[(quad * 4 + r) * 72 + j * 16 + l15] = (f16)(acc[i][j][r] * mul);
#pragma unroll
            for (int t = 0; t < 2; ++t) {
                int row = t * 8 + (lane >> 3);
                int d8 = (lane & 7) * 8;
                half8 v = *(const half8*)&T[row * 72 + d8];
                int m = m0 + wy * 64 + i * 16 + row;
                int b = m >> 11, n = m & 2047;
                *(half8*)&dst[(((size_t)(b * HEADS + h)) * NN + n) * HD + d8] = v;
            }
        }
    } else {
        __syncthreads();
        f16* T = (f16*)As + w * 512;
        int cb = c0 - 2 * DIMC;
        int dl = lane >> 2, mp = lane & 3;
#pragma unroll
        for (int i = 0; i < 4; ++i)
#pragma unroll
            for (int j = 0; j < 4; ++j) {
                half4 hv;
#pragma unroll
                for (int r = 0; r < 4; ++r) hv[r] = (f16)acc[i][j][r];
                *(half4*)&T[l15 * 20 + quad * 4] = hv;
                half4 rv = *(half4*)&T[dl * 20 + mp * 4];
                int c = cb + wx * 64 + j * 16 + dl;
                int m = m0 + wy * 64 + i * 16 + mp * 4;
                int b = m >> 11, n = m & 2047;
                int h = c >> 6, d = c & 63;
                *(half4*)&vtb[(((size_t)(b * HEADS + h)) * HD + d) * NN + n] = rv;
            }
    }
}

// ---------------- Flash attention: full-K per block, fixed-base softmax ----------------
// R16 = R11 (best measured per-dispatch attn, <=42.6us): swizzled LDS, in-reg
// P (permlane), in-reg normalization, g2l16 dbuf staging, deferred-PV pipeline,
// launch_bounds(256,2) so carried fragments stay in registers (no spill).
__global__ __launch_bounds__(256, 2) void attn_kernel(const f16* __restrict__ qb,
                                                      const f16* __restrict__ kbuf,
                                                      const f16* __restrict__ vtb,
                                                      f16* __restrict__ ao) {
    __shared__ __align__(16) f16 KV[16384];   // 32KB: buf0{K 8K|V 8K} buf1{K 8K|V 8K}
    int id = blockIdx.x;
    int xcd = id & 7, slot = id >> 3;          // slot 0..63
    int bh = xcd * 4 + (slot >> 4);            // all 16 q-tiles of a bh on one XCD
    int qt4 = slot & 15;                       // q-tile 0..15
    int n0 = qt4 * 128;
    int tid = threadIdx.x, w = tid >> 6, lane = tid & 63, l15 = lane & 15, quad = lane >> 4;
    const f16* Kbase = kbuf + (size_t)bh * NN * HD;
    const f16* Vbase = vtb + (size_t)bh * HD * NN;
    const f16* Qbase = qb + (size_t)bh * NN * HD;
    half8 qf[2][2];
#pragma unroll
    for (int qt = 0; qt < 2; ++qt) {
        const f16* qr = Qbase + (size_t)(n0 + w * 32 + qt * 16 + l15) * HD + quad * 8;
        qf[qt][0] = *(const half8*)qr;
        qf[qt][1] = *(const half8*)(qr + 32);
    }
    f32x4 ot[2][4] = {};
    f32x4 lacc[2] = {};
    half8 ones8;
#pragma unroll
    for (int j = 0; j < 8; ++j) ones8[j] = (f16)1.0f;
    int rx = (l15 & 7) << 4;                   // read-side swizzle constant
    // g2l16 source pre-swizzle (R10): lane -> (row lane>>3, slot lane&7)
    int lrow = lane >> 3;
    int scolb = ((lane & 7) << 4) ^ (lrow << 4);
    int rbase = w * 16;
    {
        char* K0 = (char*)KV;
        char* V0 = (char*)KV + 8192;
#pragma unroll
        for (int c = 0; c < 2; ++c) {
            int r0 = rbase + c * 8;
            g2l16((const char*)Kbase + (size_t)(r0 + lrow) * (HD * 2) + scolb,
                  K0 + r0 * 128);
            g2l16((const char*)Vbase + (size_t)(r0 + lrow) * (NN * 2) + scolb,
                  V0 + r0 * 128);
        }
    }
    __syncthreads();
    u32x4 pbs[2][2];     // deferred P fragments [kc][qt]
    half8 avs[2][4];     // deferred V fragments [kc][dt]
    for (int it = 0; it < NN / 64; ++it) {
        int cur = it & 1;
        char* Kc = (char*)KV + (cur << 14);
        char* Vc = Kc + 8192;
        if (it < NN / 64 - 1) {
            char* Kn = (char*)KV + ((cur ^ 1) << 14);
            char* Vn = Kn + 8192;
            int k0 = (it + 1) * 64;
#pragma unroll
            for (int c = 0; c < 2; ++c) {
                int r0 = rbase + c * 8;
                g2l16((const char*)Kbase + (size_t)(k0 + r0 + lrow) * (HD * 2) + scolb,
                      Kn + r0 * 128);
                g2l16((const char*)Vbase + (size_t)(r0 + lrow) * (NN * 2) + k0 * 2 + scolb,
                      Vn + r0 * 128);
            }
        }
        // deferred PV(it-1): pure-register MFMAs — interleaves with QK(it)'s
        // ds_read latency below (scheduler hoists the loads)
        if (it > 0) {
            __builtin_amdgcn_s_setprio(1);
#pragma unroll
            for (int kc = 0; kc < 2; ++kc)
#pragma unroll
                for (int qt = 0; qt < 2; ++qt) {
                    half8 pb8 = __builtin_bit_cast(half8, pbs[kc][qt]);
                    lacc[qt] = __builtin_amdgcn_mfma_f32_16x16x32_f16(ones8, pb8, lacc[qt], 0, 0, 0);
#pragma unroll
                    for (int dt = 0; dt < 4; ++dt)
                        ot[qt][dt] = __builtin_amdgcn_mfma_f32_16x16x32_f16(avs[kc][dt], pb8, ot[qt][dt], 0, 0, 0);
                }
            __builtin_amdgcn_s_setprio(0);
        }
        // QK(it)
        f32x4 s0[4], s1[4];
        __builtin_amdgcn_s_setprio(1);
#pragma unroll
        for (int kt = 0; kt < 4; ++kt) {
            int rb = (kt * 16 + l15) * 128;
            half8 a0 = *(const half8*)(Kc + rb + ((quad * 16) ^ rx));
            half8 a1 = *(const half8*)(Kc + rb + ((64 + quad * 16) ^ rx));
            f32x4 z0 = {};
            z0 = __builtin_amdgcn_mfma_f32_16x16x32_f16(a0, qf[0][0], z0, 0, 0, 0);
            z0 = __builtin_amdgcn_mfma_f32_16x16x32_f16(a1, qf[0][1], z0, 0, 0, 0);
            s0[kt] = z0;
            f32x4 z1 = {};
            z1 = __builtin_amdgcn_mfma_f32_16x16x32_f16(a0, qf[1][0], z1, 0, 0, 0);
            z1 = __builtin_amdgcn_mfma_f32_16x16x32_f16(a1, qf[1][1], z1, 0, 0, 0);
            s1[kt] = z1;
        }
        __builtin_amdgcn_s_setprio(0);
        // exp2 -> packed f16 u32s, fully in-register (R4)
        uint up[2][4][2];
#pragma unroll
        for (int kt = 0; kt < 4; ++kt) {
            up[0][kt][0] = __builtin_bit_cast(uint, __builtin_amdgcn_cvt_pkrtz(
                __builtin_amdgcn_exp2f(s0[kt][0]), __builtin_amdgcn_exp2f(s0[kt][1])));
            up[0][kt][1] = __builtin_bit_cast(uint, __builtin_amdgcn_cvt_pkrtz(
                __builtin_amdgcn_exp2f(s0[kt][2]), __builtin_amdgcn_exp2f(s0[kt][3])));
            up[1][kt][0] = __builtin_bit_cast(uint, __builtin_amdgcn_cvt_pkrtz(
                __builtin_amdgcn_exp2f(s1[kt][0]), __builtin_amdgcn_exp2f(s1[kt][1])));
            up[1][kt][1] = __builtin_bit_cast(uint, __builtin_amdgcn_cvt_pkrtz(
                __builtin_amdgcn_exp2f(s1[kt][2]), __builtin_amdgcn_exp2f(s1[kt][3])));
        }
        // read V(it) into regs + build P(it) fragments; MFMAs run next iter
#pragma unroll
        for (int kc = 0; kc < 2; ++kc) {
            int cb = (kc * 64 + quad * 16) ^ rx;
#pragma unroll
            for (int dt = 0; dt < 4; ++dt)
                avs[kc][dt] = *(const half8*)(Vc + (dt * 16 + l15) * 128 + cb);
#pragma unroll
            for (int qt = 0; qt < 2; ++qt) {
                u32x4 pw;
#pragma unroll
                for (int i = 0; i < 2; ++i) {
                    uint x = up[qt][kc * 2][i], y = up[qt][kc * 2 + 1][i];
                    asm volatile("v_permlane32_swap_b32 %0, %1" : "+v"(x), "+v"(y));
                    asm volatile("v_permlane16_swap_b32 %0, %1" : "+v"(x), "+v"(y));
                    pw[i] = x; pw[2 + i] = y;
                }
                pbs[kc][qt] = pw;
            }
        }
        __syncthreads();   // single barrier: syncs waves + drains DMA for tile it+1
    }
    // final PV(31)
    __builtin_amdgcn_s_setprio(1);
#pragma unroll
    for (int kc = 0; kc < 2; ++kc)
#pragma unroll
        for (int qt = 0; qt < 2; ++qt) {
            half8 pb8 = __builtin_bit_cast(half8, pbs[kc][qt]);
            lacc[qt] = __builtin_amdgcn_mfma_f32_16x16x32_f16(ones8, pb8, lacc[qt], 0, 0, 0);
#pragma unroll
            for (int dt = 0; dt < 4; ++dt)
                ot[qt][dt] = __builtin_amdgcn_mfma_f32_16x16x32_f16(avs[kc][dt], pb8, ot[qt][dt], 0, 0, 0);
        }
    __builtin_amdgcn_s_setprio(0);
    // R5: in-register normalization — lacc col=l15=q matches ot col=q (same lane)
    float inv[2] = { 1.0f / lacc[0][0], 1.0f / lacc[1][0] };
    char* Tc = (char*)KV + w * 4096;         // per-wave 32 rows x 128B, swizzled (buf0 region)
#pragma unroll
    for (int qt = 0; qt < 2; ++qt)
#pragma unroll
        for (int dt = 0; dt < 4; ++dt) {
            half4 hv;
#pragma unroll
            for (int r = 0; r < 4; ++r) hv[r] = (f16)(ot[qt][dt][r] * inv[qt]);
            *(half4*)(Tc + (qt * 16 + l15) * 128 + ((dt * 32 + quad * 8) ^ rx)) = hv;
        }
    __syncthreads();
    int b = bh >> 3, h = bh & 7;
#pragma unroll
    for (int j = 0; j < 4; ++j) {
        int nl = j * 8 + (lane >> 3);
        int d16 = (lane & 7) * 16;
        half8 v = *(const half8*)(Tc + nl * 128 + (d16 ^ ((nl & 7) << 4)));
        int n = n0 + w * 32 + nl;
        *(half8*)&ao[((size_t)(b * NN + n)) * DIMC + h * HD + (lane & 7) * 8] = v;
    }
}

// ---------------- proj GEMM 128x64 + bias + residual (R7: 2-phase dbuf) ----------------
__global__ __launch_bounds__(256) void gemm_proj(const f16* __restrict__ aob,
                                                 const f16* __restrict__ wt,
                                                 const float* __restrict__ x,
                                                 const float* __restrict__ bias,
                                                 float* __restrict__ out) {
    __shared__ __align__(16) f16 As[2 * 128 * 32];
    __shared__ __align__(16) f16 Bs[2 * 64 * 32];
    int tid = threadIdx.x;
    int w = tid >> 6, lane = tid & 63, l15 = lane & 15, quad = lane >> 4;
    int m0 = blockIdx.y * 128, c0 = blockIdx.x * 64;
    const char* Ag = (const char*)(aob + (size_t)m0 * DIMC);
    const char* Bg = (const char*)(wt + (size_t)c0 * DIMC);
    f32x4 acc[2][4] = {};
    int off0 = w * 1024 + lane * 16;
#define PSTAGE(kk, b) do { \
    _Pragma("unroll") \
    for (int c = 0; c < 2; ++c) { \
        int off = c * 4096 + off0; \
        int row = off >> 6, col = off & 63; \
        g2l16(Ag + (size_t)row * 1024 + (kk) * 64 + col, (char*)As + (b) * 8192 + c * 4096 + w * 1024); \
    } \
    { \
        int off = tid * 16; \
        int row = off >> 6, col = off & 63; \
        g2l16(Bg + (size_t)row * 1024 + (kk) * 64 + col, (char*)Bs + (b) * 4096 + w * 1024); \
    } } while (0)
    PSTAGE(0, 0);
    __syncthreads();
    for (int kk = 0; kk < 16; ++kk) {
        int cb = kk & 1;
        if (kk < 15) PSTAGE(kk + 1, cb ^ 1);
        half8 af[2], bf[4];
#pragma unroll
        for (int i = 0; i < 2; ++i)
            af[i] = *(const half8*)((const char*)As + cb * 8192 + ((w * 32 + i * 16 + l15) << 6) + quad * 16);
#pragma unroll
        for (int j = 0; j < 4; ++j)
            bf[j] = *(const half8*)((const char*)Bs + cb * 4096 + ((j * 16 + l15) << 6) + quad * 16);
#pragma unroll
        for (int i = 0; i < 2; ++i)
#pragma unroll
            for (int j = 0; j < 4; ++j)
                acc[i][j] = __builtin_amdgcn_mfma_f32_16x16x32_f16(af[i], bf[j], acc[i][j], 0, 0, 0);
        __syncthreads();
    }
#undef PSTAGE
#pragma unroll
    for (int i = 0; i < 2; ++i)
#pragma unroll
        for (int j = 0; j < 4; ++j)
#pragma unroll
            for (int r = 0; r < 4; ++r) {
                int m = m0 + w * 32 + i * 16 + quad * 4 + r;
                int c = c0 + j * 16 + l15;
                out[(size_t)m * DIMC + c] = x[(size_t)m * DIMC + c] + bias[c] + acc[i][j][r];
            }
}

extern "C" void kernel_launch(void* const* d_in, const int* in_sizes, int n_in,
                              void* d_out, int out_size, void* d_ws, size_t ws_size,
                              hipStream_t stream) {
    (void)in_sizes; (void)n_in; (void)out_size; (void)ws_size;
    const float* x     = (const float*)d_in[0];
    const float* wqkv  = (const float*)d_in[1];
    const float* wproj = (const float*)d_in[2];
    const float* bproj = (const float*)d_in[3];
    const float* gamma = (const float*)d_in[4];
    const float* beta  = (const float*)d_in[5];
    float* out = (float*)d_out;

    char* ws = (char*)d_ws;
    f16* xn     = (f16*)ws;                 ws += (size_t)MM * DIMC * 2;
    f16* wqkvt  = (f16*)ws;                 ws += (size_t)NQKV * DIMC * 2;
    f16* wprojt = (f16*)ws;                 ws += (size_t)DIMC * DIMC * 2;
    f16* qbuf   = (f16*)ws;                 ws += (size_t)MM * DIMC * 2;
    f16* kbuf   = (f16*)ws;                 ws += (size_t)MM * DIMC * 2;
    f16* vtbuf  = (f16*)ws;                 ws += (size_t)MM * DIMC * 2;
    f16* aobuf  = (f16*)ws;                 ws += (size_t)MM * DIMC * 2;

    prep_kernel<<<2048 + 384 + 128, 256, 0, stream>>>(x, gamma, beta, wqkv, wproj,
                                                      xn, wqkvt, wprojt);
    gemm_qkv<<<dim3(NQKV / 128, MM / 128), 256, 0, stream>>>(xn, wqkvt, qbuf, kbuf, vtbuf);
    attn_kernel<<<NN / 128 * BB * HEADS, 256, 0, stream>>>(qbuf, kbuf, vtbuf, aobuf);
    gemm_proj<<<dim3(DIMC / 64, MM / 128), 256, 0, stream>>>(aobuf, wprojt, x, bproj, out);
}